// Round 2
// baseline (240.348 us; speedup 1.0000x reference)
//
#include <hip/hip_runtime.h>
#include <math.h>

// Problem constants (fixed by the reference).
#define BB    1024
#define SS    277
#define RR    76
#define ZZ    56
#define NLHS  24
#define NROWS (BB*SS)                      // 283648
#define ROWS_PER_BLOCK 256                 // rows per GROUP (reduction unit, fixed for bit-exact partials)
#define NBCE (NROWS/ROWS_PER_BLOCK)        // 1108 groups (partials layout, unchanged)
#define NMOM ZZ                            // 56 (placed FIRST in the grid)
#define NBLK (NBCE + NMOM)                 // 1164 partials total (unchanged)
#define PBLK 256                           // persistent BCE blocks, 1 per CU
#define F4ROW 19                           // 76 floats = 19 float4 per row
#define F4BLK (ROWS_PER_BLOCK*F4ROW)       // 4864 float4 = 77824 B per group tile
#define BLK_ELEMS (ROWS_PER_BLOCK*RR)      // 19456
#define TOTAL_ELEMS 21558272.0             // B*S*R

static_assert(NROWS % ROWS_PER_BLOCK == 0, "rows divide groups");

#define LN2F  0.69314718056f
#define NLN2F (-144.26950409f)   /* -100 / ln2 */

// Direct global->LDS copy, 16 B per lane. LDS dest = wave-uniform base +
// lane*16 in HW; our linear layout (consecutive lanes -> consecutive float4
// slots) matches exactly (guide §5 caveat).
__device__ __forceinline__ void gload_lds16(const float4* g, float4* l) {
    auto gp = reinterpret_cast<const __attribute__((address_space(1))) unsigned int*>(
        reinterpret_cast<uintptr_t>(g));
    auto lp = reinterpret_cast<__attribute__((address_space(3))) unsigned int*>(
        reinterpret_cast<uintptr_t>(l));
    __builtin_amdgcn_global_load_lds(gp, lp, 16, 0, 0);
}

// R6: persistent double-buffered pipeline. R5 post-mortem: both R4 and R5
// ran at 172MB / ~2.07 TB/s — memory-pipe DUTY CYCLE bound (burst-load then
// compute with pipe idle; only 2 blocks/CU to interleave). Here 256
// persistent blocks (1/CU) each ping-pong two 76KB LDS tiles: stage group
// g+1 (targets->regs->scan, model->LDS via global_load_lds) while computing
// group g from the resident tile; the per-group __syncthreads vmcnt(0)
// drain is the pipeline clock (T3/T14). Per-row math, 256-row group
// reduction, and partials layout are verbatim R5 -> bit-identical output.
__global__ __launch_bounds__(256, 1) void fused_kernel(
    const float* __restrict__ model,
    const float* __restrict__ target,
    const float* __restrict__ masks,
    const int*   __restrict__ ind_to_lhs,
    const float* __restrict__ mu,
    double* __restrict__ partials)
{
    __shared__ float4        sx[2][F4BLK];      // 155648 B double-buffered model tiles
    __shared__ unsigned int  smb[NLHS*4];       // 96-bit mask per lhs, padded
    __shared__ int           sm_lhs[RR];
    __shared__ unsigned char sm_idx[2][ROWS_PER_BLOCK];
    __shared__ float         sm_red[2][4];
    __shared__ float         sdot[4][64];       // mom path
    __shared__ float         ssum[4];

    const int tid = threadIdx.x;

    if (blockIdx.x < NMOM) {
        // ---------------- mom path: var[:,j] for j = blockIdx ----------------
        const int j    = blockIdx.x;
        const int w    = tid >> 6;
        const int lane = tid & 63;
        const int i    = (lane < ZZ) ? lane : 0;
        float dot = 0.f, s1 = 0.f;
        const int b0 = 256*w;
        #pragma unroll 4
        for (int b = b0; b < b0 + 256; ++b) {
            const float c = mu[b*ZZ + j];     // wave-uniform broadcast
            const float a = mu[b*ZZ + i];     // coalesced across lanes
            dot = fmaf(a, c, dot);
            s1 += c;
        }
        sdot[w][lane] = dot;
        if (lane == 0) ssum[w] = s1;
        __syncthreads();
        if (w == 0) {
            float term = 0.f;
            if (lane < ZZ) {
                const float var = (sdot[0][lane]+sdot[1][lane]+sdot[2][lane]+sdot[3][lane]) * (1.f/BB);
                const float ve  = var - ((lane == j) ? 1.f : 0.f);
                term = tanhf(ve) * ve * (1.f/(ZZ*ZZ));
                if (lane == j) {
                    const float am = (ssum[0]+ssum[1]+ssum[2]+ssum[3]) * (1.f/BB);
                    term = fmaf(am*am, 1.f/ZZ, term);
                }
            }
            #pragma unroll
            for (int off = 32; off; off >>= 1) term += __shfl_xor(term, off, 64);
            if (lane == 0) partials[blockIdx.x] = (double)term;
        }
        return;
    }

    // ---------------- bce path: persistent, groups g = bce0 + k*PBLK ----------------
    const int bce0 = blockIdx.x - NMOM;   // 0..PBLK-1

    if (tid < NLHS*4) smb[tid] = 0u;
    sm_idx[0][tid] = 0;                   // safety init (one-hot always overwrites)
    sm_idx[1][tid] = 0;
    __syncthreads();

    // Pack masks into bitmasks (parallel, LDS atomicOr). L2-resident reads.
    for (int e = tid; e < NLHS*RR; e += 256) {
        const int lhs = e / RR;
        const int r   = e - lhs*RR;
        if (masks[e] > 0.5f)
            atomicOr(&smb[lhs*4 + (r >> 5)], 1u << (r & 31));
    }
    if (tid < RR) sm_lhs[tid] = ind_to_lhs[tid];

    // ---- prologue: stage + scan first group into slot 0 (no overlap, once) ----
    {
        const size_t base = (size_t)bce0 * BLK_ELEMS;
        const float4* g4 = (const float4*)(model + base);
        #pragma unroll
        for (int k = 0; k < F4ROW; ++k)
            gload_lds16(g4 + tid + 256*k, &sx[0][tid + 256*k]);
        const float4* t4 = (const float4*)(target + base);
        #pragma unroll
        for (int k = 0; k < F4ROW; ++k) {
            const int v4 = tid + 256*k;
            const float4 tv = t4[v4];
            int he = -1;
            const int e = v4*4;
            if (tv.x > 0.5f) he = e;
            if (tv.y > 0.5f) he = e+1;
            if (tv.z > 0.5f) he = e+2;
            if (tv.w > 0.5f) he = e+3;
            if (he >= 0) {
                const int row = he / RR;
                sm_idx[0][row] = (unsigned char)(he - row*RR);
            }
        }
    }
    __syncthreads();   // drains prologue stages (vmcnt 0); smb/sm_lhs/idx0 visible

    int nb = 0;
    for (int g = bce0; g < NBCE; g += PBLK) {
        const int g2 = g + PBLK;

        // [A]+[B] prefetch next group: targets (issued FIRST) -> regs -> scan;
        // model -> sx[nb^1] via global_load_lds (stays in flight through the
        // compute phase; in-order vmcnt means the scan waits only on targets).
        if (g2 < NBCE) {
            const size_t base2 = (size_t)g2 * BLK_ELEMS;
            const float4* t4 = (const float4*)(target + base2);
            float4 t[F4ROW];
            #pragma unroll
            for (int k = 0; k < F4ROW; ++k) t[k] = t4[tid + 256*k];
            const float4* g4 = (const float4*)(model + base2);
            #pragma unroll
            for (int k = 0; k < F4ROW; ++k)
                gload_lds16(g4 + tid + 256*k, &sx[nb^1][tid + 256*k]);
            // Coalesced one-hot scan -> sm_idx[nb^1]. One writer per row.
            #pragma unroll
            for (int k = 0; k < F4ROW; ++k) {
                const int v4 = tid + 256*k;
                const float4 tv = t[k];
                int he = -1;
                const int e = v4*4;
                if (tv.x > 0.5f) he = e;
                if (tv.y > 0.5f) he = e+1;
                if (tv.z > 0.5f) he = e+2;
                if (tv.w > 0.5f) he = e+3;
                if (he >= 0) {
                    const int row = he / RR;
                    sm_idx[nb^1][row] = (unsigned char)(he - row*RR);
                }
            }
        }

        // [C] compute group g from sx[nb] / sm_idx[nb] (R5-verbatim math).
        const int true_r = (int)sm_idx[nb][tid];
        const int lhs    = sm_lhs[true_r];
        const unsigned int mw0 = smb[lhs*4 + 0];
        const unsigned int mw1 = smb[lhs*4 + 1];
        const unsigned int mw2 = smb[lhs*4 + 2];

        const float4* xr = &sx[nb][tid*F4ROW];   // byte addr tid*304, 16B-aligned

        // Pass A: masked row max.
        float mx = -1e30f;
        #pragma unroll
        for (int k = 0; k < F4ROW; ++k) {
            const float4 v = xr[k];
            #pragma unroll
            for (int c = 0; c < 4; ++c) {
                const int r = k*4 + c;
                const unsigned int mw = (r < 32) ? mw0 : ((r < 64) ? mw1 : mw2);
                const bool un = (mw >> (r & 31)) & 1u;
                const float xm = un ? (&v.x)[c] : -1e30f;
                mx = fmaxf(mx, xm);
            }
        }

        // Pass B: e_r = exp(x_r - mx) (masked -> 0), sum.
        float s = 0.f;
        #pragma unroll
        for (int k = 0; k < F4ROW; ++k) {
            const float4 v = xr[k];
            #pragma unroll
            for (int c = 0; c < 4; ++c) {
                const int r = k*4 + c;
                const unsigned int mw = (r < 32) ? mw0 : ((r < 64) ? mw1 : mw2);
                const bool un = (mw >> (r & 31)) & 1u;
                const float xm = un ? (&v.x)[c] : -1e30f;
                s += __expf(xm - mx);
            }
        }

        // Pass C: clamped log(1-p) over ALL r (log2-domain), plus p at target.
        const float inv = 1.f / s;
        float sum_l2 = 0.f;
        float p_true = 0.f;
        #pragma unroll
        for (int k = 0; k < F4ROW; ++k) {
            const float4 v = xr[k];
            #pragma unroll
            for (int c = 0; c < 4; ++c) {
                const int r = k*4 + c;
                const unsigned int mw = (r < 32) ? mw0 : ((r < 64) ? mw1 : mw2);
                const bool un = (mw >> (r & 31)) & 1u;
                const float xm = un ? (&v.x)[c] : -1e30f;
                const float ev = __expf(xm - mx);
                const float p  = ev * inv;
                const float l2 = __log2f(1.f - p);
                sum_l2 += fmaxf(l2, NLN2F);
                if (r == true_r) p_true = p;
            }
        }
        float row_sum = LN2F * sum_l2;
        const float l1c_t = fmaxf(LN2F * __log2f(1.f - p_true), -100.f);
        const float lp_t  = fmaxf(__logf(p_true), -100.f);   // p_true==0 (masked) -> -100
        row_sum += lp_t - l1c_t;

        // Block reduce (identical grouping: wave butterfly, (s0+s1)+(s2+s3)).
        #pragma unroll
        for (int off = 32; off; off >>= 1) row_sum += __shfl_xor(row_sum, off, 64);
        if ((tid & 63) == 0) sm_red[nb][tid >> 6] = row_sum;

        // [D] pipeline clock: drains the g+1 stages (vmcnt 0) + makes scan
        // writes and sm_red visible; buffers safe to swap after this.
        __syncthreads();
        if (tid == 0)
            partials[NMOM + g] = (double)((sm_red[nb][0] + sm_red[nb][1]) + (sm_red[nb][2] + sm_red[nb][3]));
        nb ^= 1;
    }
}

// Sum NBCE bce partials + NMOM mom partials with the right scales. (Unchanged.)
__global__ __launch_bounds__(256) void final_kernel(
    const double* __restrict__ partials, float* __restrict__ out)
{
    __shared__ double sred[4];
    const int tid = threadIdx.x;
    double s = 0.0;
    for (int k = NMOM + tid; k < NBLK; k += 256) s += partials[k];
    double m = (tid < NMOM) ? partials[tid] : 0.0;
    double val = s * (-(double)SS / TOTAL_ELEMS) + m;
    #pragma unroll
    for (int off = 32; off; off >>= 1) val += __shfl_xor(val, off, 64);
    if ((tid & 63) == 0) sred[tid >> 6] = val;
    __syncthreads();
    if (tid == 0) out[0] = (float)((sred[0] + sred[1]) + (sred[2] + sred[3]));
}

extern "C" void kernel_launch(void* const* d_in, const int* in_sizes, int n_in,
                              void* d_out, int out_size, void* d_ws, size_t ws_size,
                              hipStream_t stream) {
    const float* model  = (const float*)d_in[0];   // [B,S,R]
    const float* mu     = (const float*)d_in[1];   // [B,Z]
    // d_in[2] = log_var — unused by the reference output
    const float* target = (const float*)d_in[3];   // [B,S,R] one-hot
    const float* masks  = (const float*)d_in[4];   // [NLHS,R]
    const int*   ind    = (const int*)  d_in[5];   // [R]
    float* out  = (float*)d_out;
    double* acc = (double*)d_ws;   // [0..NMOM) mom partials, [NMOM..NBLK) bce partials

    fused_kernel<<<NMOM + PBLK, ROWS_PER_BLOCK, 0, stream>>>(model, target, masks, ind, mu, acc);
    final_kernel<<<1, 256, 0, stream>>>(acc, out);
}

// Round 3
// 233.561 us; speedup vs baseline: 1.0291x; 1.0291x over previous
//
#include <hip/hip_runtime.h>
#include <math.h>

// Problem constants (fixed by the reference).
#define BB    1024
#define SS    277
#define RR    76
#define ZZ    56
#define NLHS  24
#define NROWS (BB*SS)                      // 283648
#define ROWS_PER_BLOCK 256                 // rows per group (reduction unit, bit-exact)
#define NBCE (NROWS/ROWS_PER_BLOCK)        // 1108 groups
#define NMOM ZZ                            // 56 mom partials (first in layout)
#define NBLK (NBCE + NMOM)                 // 1164 partials total (unchanged layout)
#define F4ROW 19                           // 76 floats = 19 float4 per row
#define F4BLK (ROWS_PER_BLOCK*F4ROW)       // 4864 float4 = 77824 B LDS tile
#define BLK_ELEMS (ROWS_PER_BLOCK*RR)      // 19456
#define F4TOTAL (NROWS*F4ROW)              // 5389312 float4 in target tensor
#define SCAN_BLOCKS 2048                   // grid-stride scan width (8 blocks/CU)
#define TOTAL_ELEMS 21558272.0             // harness-verified constant (do not touch)

static_assert(NROWS % ROWS_PER_BLOCK == 0, "rows divide groups");

#define LN2F  0.69314718056f
#define NLN2F (-144.26950409f)   /* -100 / ln2 */

// Direct global->LDS copy, 16 B per lane. LDS dest = wave-uniform base +
// lane*16 in HW; linear layout (consecutive lanes -> consecutive float4
// slots) matches exactly (guide §5 caveat).
__device__ __forceinline__ void gload_lds16(const float4* g, float4* l) {
    auto gp = reinterpret_cast<const __attribute__((address_space(1))) unsigned int*>(
        reinterpret_cast<uintptr_t>(g));
    auto lp = reinterpret_cast<__attribute__((address_space(3))) unsigned int*>(
        reinterpret_cast<uintptr_t>(l));
    __builtin_amdgcn_global_load_lds(gp, lp, 16, 0, 0);
}

// R7 split. Evidence: R4/R5/R6 all deliver 7.8-8.3 GB/s per CU regardless of
// structure (2.06/2.06/1.8 TB/s aggregate on 172MB) -> the thread-per-row
// block shape has a per-CU MLP/duty-cycle ceiling, while m13-style
// grid-stride streaming reaches 24.6 GB/s/CU. So: (1) move the one-hot
// target scan (half the bytes) into a max-occupancy grid-stride PREPASS
// that emits uint8 idx[NROWS]; (2) the BCE kernel streams only the model
// through the proven R5 structure. Mom path rides in the prepass.

// ---------------------------------------------------------------------------
// Prepass: blocks [0,NMOM) = mom path (verbatim); blocks [NMOM, NMOM+SCAN_BLOCKS)
// = one-hot scan, pure streaming, no LDS, no barriers.
// ---------------------------------------------------------------------------
__global__ __launch_bounds__(256) void prepass_kernel(
    const float* __restrict__ target,
    const float* __restrict__ mu,
    unsigned char* __restrict__ idx,
    double* __restrict__ partials)
{
    __shared__ float sdot[4][64];
    __shared__ float ssum[4];

    const int tid = threadIdx.x;

    if (blockIdx.x < NMOM) {
        // ---------------- mom path: var[:,j] for j = blockIdx (verbatim) ----
        const int j    = blockIdx.x;
        const int w    = tid >> 6;
        const int lane = tid & 63;
        const int i    = (lane < ZZ) ? lane : 0;
        float dot = 0.f, s1 = 0.f;
        const int b0 = 256*w;
        #pragma unroll 4
        for (int b = b0; b < b0 + 256; ++b) {
            const float c = mu[b*ZZ + j];     // wave-uniform broadcast
            const float a = mu[b*ZZ + i];     // coalesced across lanes
            dot = fmaf(a, c, dot);
            s1 += c;
        }
        sdot[w][lane] = dot;
        if (lane == 0) ssum[w] = s1;
        __syncthreads();
        if (w == 0) {
            float term = 0.f;
            if (lane < ZZ) {
                const float var = (sdot[0][lane]+sdot[1][lane]+sdot[2][lane]+sdot[3][lane]) * (1.f/BB);
                const float ve  = var - ((lane == j) ? 1.f : 0.f);
                term = tanhf(ve) * ve * (1.f/(ZZ*ZZ));
                if (lane == j) {
                    const float am = (ssum[0]+ssum[1]+ssum[2]+ssum[3]) * (1.f/BB);
                    term = fmaf(am*am, 1.f/ZZ, term);
                }
            }
            #pragma unroll
            for (int off = 32; off; off >>= 1) term += __shfl_xor(term, off, 64);
            if (lane == 0) partials[blockIdx.x] = (double)term;
        }
        return;
    }

    // ---------------- one-hot scan: target -> idx[row] ----------------------
    // Grid-stride, 2-deep manual batching for guaranteed independent loads in
    // flight. A float4 never straddles rows (76 = 19 f4); exactly one writer
    // per row globally (one-hot), so plain byte stores, no init, no atomics.
    const float4* t4 = (const float4*)target;
    const int STRIDE = SCAN_BLOCKS*256;
    int v4 = (blockIdx.x - NMOM)*256 + tid;
    while (v4 < F4TOTAL) {
        const float4 a = t4[v4];
        const int v4b = v4 + STRIDE;
        const bool hb = (v4b < F4TOTAL);
        float4 b;
        if (hb) b = t4[v4b];

        {
            int he = -1;
            const int e = v4*4;
            if (a.x > 0.5f) he = e;
            if (a.y > 0.5f) he = e+1;
            if (a.z > 0.5f) he = e+2;
            if (a.w > 0.5f) he = e+3;
            if (he >= 0) {
                const int row = he / RR;
                idx[row] = (unsigned char)(he - row*RR);
            }
        }
        if (hb) {
            int he = -1;
            const int e = v4b*4;
            if (b.x > 0.5f) he = e;
            if (b.y > 0.5f) he = e+1;
            if (b.z > 0.5f) he = e+2;
            if (b.w > 0.5f) he = e+3;
            if (he >= 0) {
                const int row = he / RR;
                idx[row] = (unsigned char)(he - row*RR);
            }
        }
        v4 += 2*STRIDE;
    }
}

// ---------------------------------------------------------------------------
// BCE kernel: 1108 blocks, one 256-row group each, model staged HBM->LDS via
// global_load_lds (R5-proven). Mask-pack global reads happen BEFORE the stage
// issues so no consume forces a premature vmcnt drain; the single barrier is
// the only vmcnt(0). Per-row math + reduction tree verbatim R5 (absmax 0).
// ---------------------------------------------------------------------------
__global__ __launch_bounds__(256, 2) void bce_kernel(
    const float* __restrict__ model,
    const float* __restrict__ masks,
    const int*   __restrict__ ind_to_lhs,
    const unsigned char* __restrict__ idx,
    double* __restrict__ partials)
{
    __shared__ float4        sx[F4BLK];        // 77824 B staged model tile
    __shared__ unsigned int  smb[NLHS*4];      // 96-bit mask per lhs, padded
    __shared__ int           sm_lhs[RR];
    __shared__ float         sm_red[4];

    const int tid = threadIdx.x;
    const int g   = blockIdx.x;
    const size_t blk_base = (size_t)g * BLK_ELEMS;

    if (tid < NLHS*4) smb[tid] = 0u;
    __syncthreads();   // nothing in flight yet -> cheap barrier

    // Row index for this thread (tiny coalesced byte load; issued early).
    const int true_r = (int)idx[(size_t)g * ROWS_PER_BLOCK + tid];

    // Pack masks into bitmasks (parallel, LDS atomicOr). These global reads
    // are issued AND consumed before the stages are issued.
    for (int e = tid; e < NLHS*RR; e += 256) {
        const int lhs = e / RR;
        const int r   = e - lhs*RR;
        if (masks[e] > 0.5f)
            atomicOr(&smb[lhs*4 + (r >> 5)], 1u << (r & 31));
    }
    if (tid < RR) sm_lhs[tid] = ind_to_lhs[tid];

    // Stage the model tile (coalesced, direct to LDS).
    {
        const float4* g4 = (const float4*)(model + blk_base);
        #pragma unroll
        for (int k = 0; k < F4ROW; ++k)
            gload_lds16(g4 + tid + 256*k, &sx[tid + 256*k]);
    }
    __syncthreads();   // drains stages (vmcnt 0); smb/sm_lhs visible

    // --- per-row compute from LDS (verbatim R5 math) ---
    const int lhs    = sm_lhs[true_r];
    const unsigned int mw0 = smb[lhs*4 + 0];
    const unsigned int mw1 = smb[lhs*4 + 1];
    const unsigned int mw2 = smb[lhs*4 + 2];

    const float4* xr = &sx[tid*F4ROW];   // byte addr tid*304, 16B-aligned
    // Row stride = 76 words == 12 mod 32 -> 64 lanes' b128 bases cover the 8
    // aligned 4-bank groups 8x each: conflict-free, no padding needed.

    // Pass A: masked row max.
    float mx = -1e30f;
    #pragma unroll
    for (int k = 0; k < F4ROW; ++k) {
        const float4 v = xr[k];
        #pragma unroll
        for (int c = 0; c < 4; ++c) {
            const int r = k*4 + c;
            const unsigned int mw = (r < 32) ? mw0 : ((r < 64) ? mw1 : mw2);
            const bool un = (mw >> (r & 31)) & 1u;
            const float xm = un ? (&v.x)[c] : -1e30f;
            mx = fmaxf(mx, xm);
        }
    }

    // Pass B: e_r = exp(x_r - mx) (masked -> 0), sum.
    float s = 0.f;
    #pragma unroll
    for (int k = 0; k < F4ROW; ++k) {
        const float4 v = xr[k];
        #pragma unroll
        for (int c = 0; c < 4; ++c) {
            const int r = k*4 + c;
            const unsigned int mw = (r < 32) ? mw0 : ((r < 64) ? mw1 : mw2);
            const bool un = (mw >> (r & 31)) & 1u;
            const float xm = un ? (&v.x)[c] : -1e30f;
            s += __expf(xm - mx);
        }
    }

    // Pass C: clamped log(1-p) over ALL r (log2-domain), plus p at target.
    const float inv = 1.f / s;
    float sum_l2 = 0.f;
    float p_true = 0.f;
    #pragma unroll
    for (int k = 0; k < F4ROW; ++k) {
        const float4 v = xr[k];
        #pragma unroll
        for (int c = 0; c < 4; ++c) {
            const int r = k*4 + c;
            const unsigned int mw = (r < 32) ? mw0 : ((r < 64) ? mw1 : mw2);
            const bool un = (mw >> (r & 31)) & 1u;
            const float xm = un ? (&v.x)[c] : -1e30f;
            const float ev = __expf(xm - mx);
            const float p  = ev * inv;
            const float l2 = __log2f(1.f - p);
            sum_l2 += fmaxf(l2, NLN2F);
            if (r == true_r) p_true = p;
        }
    }
    float row_sum = LN2F * sum_l2;
    // Swap the true_r element's non-target term for the target term.
    const float l1c_t = fmaxf(LN2F * __log2f(1.f - p_true), -100.f);
    const float lp_t  = fmaxf(__logf(p_true), -100.f);   // p_true==0 (masked) -> -100
    row_sum += lp_t - l1c_t;

    // Block reduce (identical grouping: wave butterfly, (s0+s1)+(s2+s3)).
    #pragma unroll
    for (int off = 32; off; off >>= 1) row_sum += __shfl_xor(row_sum, off, 64);
    if ((tid & 63) == 0) sm_red[tid >> 6] = row_sum;
    __syncthreads();
    if (tid == 0)
        partials[NMOM + g] = (double)((sm_red[0] + sm_red[1]) + (sm_red[2] + sm_red[3]));
}

// Sum NBCE bce partials + NMOM mom partials with the right scales. (Unchanged.)
__global__ __launch_bounds__(256) void final_kernel(
    const double* __restrict__ partials, float* __restrict__ out)
{
    __shared__ double sred[4];
    const int tid = threadIdx.x;
    double s = 0.0;
    for (int k = NMOM + tid; k < NBLK; k += 256) s += partials[k];
    double m = (tid < NMOM) ? partials[tid] : 0.0;
    double val = s * (-(double)SS / TOTAL_ELEMS) + m;
    #pragma unroll
    for (int off = 32; off; off >>= 1) val += __shfl_xor(val, off, 64);
    if ((tid & 63) == 0) sred[tid >> 6] = val;
    __syncthreads();
    if (tid == 0) out[0] = (float)((sred[0] + sred[1]) + (sred[2] + sred[3]));
}

extern "C" void kernel_launch(void* const* d_in, const int* in_sizes, int n_in,
                              void* d_out, int out_size, void* d_ws, size_t ws_size,
                              hipStream_t stream) {
    const float* model  = (const float*)d_in[0];   // [B,S,R]
    const float* mu     = (const float*)d_in[1];   // [B,Z]
    // d_in[2] = log_var — unused by the reference output
    const float* target = (const float*)d_in[3];   // [B,S,R] one-hot
    const float* masks  = (const float*)d_in[4];   // [NLHS,R]
    const int*   ind    = (const int*)  d_in[5];   // [R]
    float* out  = (float*)d_out;

    // Workspace: [0..NBLK) double partials, then NROWS uint8 row indices.
    double*        acc = (double*)d_ws;
    unsigned char* idx = (unsigned char*)d_ws + (size_t)NBLK * sizeof(double);

    prepass_kernel<<<NMOM + SCAN_BLOCKS, 256, 0, stream>>>(target, mu, idx, acc);
    bce_kernel<<<NBCE, 256, 0, stream>>>(model, masks, ind, idx, acc);
    final_kernel<<<1, 256, 0, stream>>>(acc, out);
}

// Round 5
// 203.777 us; speedup vs baseline: 1.1795x; 1.1462x over previous
//
#include <hip/hip_runtime.h>
#include <math.h>

// Problem constants (fixed by the reference).
#define BB    1024
#define SS    277
#define RR    76
#define ZZ    56
#define NLHS  24
#define NROWS (BB*SS)                      // 283648
#define ROWS_PER_BLOCK 256                 // rows per group (reduction unit, bit-exact)
#define NBCE (NROWS/ROWS_PER_BLOCK)        // 1108 groups
#define NMOM ZZ                            // 56 mom partials (first in layout)
#define NBLK (NBCE + NMOM)                 // 1164 partials (layout unchanged)
#define F4ROW 19                           // 76 floats = 19 float4 per row
#define F4BLK (ROWS_PER_BLOCK*F4ROW)       // 4864 float4 = 77824 B tile
#define BLK_ELEMS (ROWS_PER_BLOCK*RR)      // 19456
#define ROWS_PER_WAVE 64
#define F4WAVE (ROWS_PER_WAVE*F4ROW)       // 1216 float4 per wave
#define NMASK (NLHS*RR)                    // 1824
#define NMASK4 (NMASK/4)                   // 456 (exact)
#define TOTAL_ELEMS 21558272.0             // harness-verified constant

static_assert(NROWS % ROWS_PER_BLOCK == 0, "rows divide groups");
static_assert(NMASK4*4 == NMASK, "masks divisible by float4");

#define LN2F  0.69314718056f
#define NLN2F (-144.26950409f)   /* -100 / ln2 */

// Direct global->LDS copy, 16 B per lane. HW dest = wave-uniform base +
// lane*16; our mapping (slot = w*F4WAVE + k*64 + lane) is lane-contiguous
// 16B, so the per-lane pointer we pass equals base+lane*16 exactly.
__device__ __forceinline__ void gload_lds16(const float4* g, float4* l) {
    auto gp = reinterpret_cast<const __attribute__((address_space(1))) unsigned int*>(
        reinterpret_cast<uintptr_t>(g));
    auto lp = reinterpret_cast<__attribute__((address_space(3))) unsigned int*>(
        reinterpret_cast<uintptr_t>(l));
    __builtin_amdgcn_global_load_lds(gp, lp, 16, 0, 0);
}

// R8 (resubmit; prior round was an infra failure, kernel never ran).
// Wave-autonomous pipeline. Evidence (R4-R7): four diverse structures all
// deliver 1.65-2.1 TB/s effective reads while the harness fill writes at
// 6.5 TB/s; the shared trait of the slow block-shaped ones is memory-pipe
// drains at phase boundaries (__syncthreads => s_waitcnt vmcnt(0)). Here
// each of the 4 waves per block owns 64 rows end-to-end: issues masks ->
// targets -> global_load_lds stages, scans targets while stages fly, builds
// PER-WAVE mask-bitmap/lhs/idx tables (wave-local LDS, no barrier), then one
// manual per-wave vmcnt(0)+sched_barrier and computes from LDS. The only
// __syncthreads is the final 4-value combine (nothing outstanding).
// 8 waves/CU run phase-staggered -> reads continuously in flight.
// Math + reduce tree verbatim R5 -> bit-identical output.
struct BceShared {
    float4        sx[F4BLK];                    // 77824 B staged model tile
    unsigned int  swb[4][NLHS*4];               // per-wave 96-bit masks (padded)
    int           swl[4][RR];                   // per-wave lhs table
    unsigned char sidx[4][ROWS_PER_WAVE];       // per-wave one-hot idx
    float         sm_red[4];
};
struct MomShared {
    float sdot[4][64];
    float ssum[4];
};
union SharedU { BceShared b; MomShared m; };

__global__ __launch_bounds__(256, 2) void fused_kernel(
    const float* __restrict__ model,
    const float* __restrict__ target,
    const float* __restrict__ masks,
    const int*   __restrict__ ind_to_lhs,
    const float* __restrict__ mu,
    double* __restrict__ partials)
{
    __shared__ SharedU sh;
    const int tid = threadIdx.x;

    if (blockIdx.x < NMOM) {
        // ---------------- mom path: var[:,j] for j = blockIdx (verbatim) ----
        const int j    = blockIdx.x;
        const int w    = tid >> 6;
        const int lane = tid & 63;
        const int i    = (lane < ZZ) ? lane : 0;
        float dot = 0.f, s1 = 0.f;
        const int b0 = 256*w;
        #pragma unroll 4
        for (int b = b0; b < b0 + 256; ++b) {
            const float c = mu[b*ZZ + j];     // wave-uniform broadcast
            const float a = mu[b*ZZ + i];     // coalesced across lanes
            dot = fmaf(a, c, dot);
            s1 += c;
        }
        sh.m.sdot[w][lane] = dot;
        if (lane == 0) sh.m.ssum[w] = s1;
        __syncthreads();
        if (w == 0) {
            float term = 0.f;
            if (lane < ZZ) {
                const float var = (sh.m.sdot[0][lane]+sh.m.sdot[1][lane]+sh.m.sdot[2][lane]+sh.m.sdot[3][lane]) * (1.f/BB);
                const float ve  = var - ((lane == j) ? 1.f : 0.f);
                term = tanhf(ve) * ve * (1.f/(ZZ*ZZ));
                if (lane == j) {
                    const float am = (sh.m.ssum[0]+sh.m.ssum[1]+sh.m.ssum[2]+sh.m.ssum[3]) * (1.f/BB);
                    term = fmaf(am*am, 1.f/ZZ, term);
                }
            }
            #pragma unroll
            for (int off = 32; off; off >>= 1) term += __shfl_xor(term, off, 64);
            if (lane == 0) partials[blockIdx.x] = (double)term;
        }
        return;
    }

    // ---------------- bce path: 4 autonomous waves, 64 rows each ------------
    const int bce_blk = blockIdx.x - NMOM;
    const int w    = tid >> 6;
    const int lane = tid & 63;
    const size_t blk_base = (size_t)bce_blk * BLK_ELEMS;

    // (1) small loads FIRST (in-order vmcnt retirement: consuming these later
    // waits only on them, not on the big streams issued after).
    float4 mv[8];                                  // masks as 456 float4
    {
        const float4* m4 = (const float4*)masks;
        #pragma unroll
        for (int k = 0; k < 7; ++k) mv[k] = m4[lane + 64*k];
        mv[7] = (lane + 448 < NMASK4) ? m4[lane + 448] : make_float4(0.f,0.f,0.f,0.f);
    }
    const int ivA = ind_to_lhs[lane];                               // rows 0..63
    const int ivB = (lane < RR-64) ? ind_to_lhs[64 + lane] : 0;     // lanes 0..11

    // (2) this wave's 19 coalesced target float4 loads -> registers.
    float4 t[F4ROW];
    {
        const float4* t4 = (const float4*)(target + blk_base) + w*F4WAVE;
        #pragma unroll
        for (int k = 0; k < F4ROW; ++k) t[k] = t4[k*64 + lane];
    }

    // (3) this wave's 19 global->LDS stages of ITS OWN 64 rows (stay in
    // flight through everything below until the manual vmcnt(0)).
    {
        const float4* g4 = (const float4*)(model + blk_base) + w*F4WAVE;
        float4*       l4 = sh.b.sx + w*F4WAVE;
        #pragma unroll
        for (int k = 0; k < F4ROW; ++k)
            gload_lds16(g4 + k*64 + lane, l4 + k*64 + lane);
    }

    // (4) per-wave tables (wave-local LDS: program order per wave suffices,
    // no barrier). Init bitmap, then pack from mv (waits masks loads only).
    if (lane < 48) { sh.b.swb[w][lane] = 0u; sh.b.swb[w][lane + 48] = 0u; }
    #pragma unroll
    for (int k = 0; k < 8; ++k) {
        const int q = lane + 64*k;
        if (q < NMASK4) {
            const float4 m = mv[k];
            #pragma unroll
            for (int c = 0; c < 4; ++c) {
                if ((&m.x)[c] > 0.5f) {
                    const int e   = q*4 + c;
                    const int lhs = e / RR;
                    const int r   = e - lhs*RR;
                    atomicOr(&sh.b.swb[w][lhs*4 + (r >> 5)], 1u << (r & 31));
                }
            }
        }
    }
    sh.b.swl[w][lane] = ivA;
    if (lane < RR-64) sh.b.swl[w][64 + lane] = ivB;
    sh.b.sidx[w][lane] = 0;   // safety (one-hot always overwrites)

    // (5) one-hot scan of THIS wave's rows (waits target loads; stages fly).
    // A float4 never straddles rows (76 = 19 f4); one writer per row.
    #pragma unroll
    for (int k = 0; k < F4ROW; ++k) {
        const int v4 = w*F4WAVE + k*64 + lane;    // block-local f4 index
        const float4 tv = t[k];
        int he = -1;
        const int e = v4*4;
        if (tv.x > 0.5f) he = e;
        if (tv.y > 0.5f) he = e+1;
        if (tv.z > 0.5f) he = e+2;
        if (tv.w > 0.5f) he = e+3;
        if (he >= 0) {
            const int row = he / RR;              // in [w*64, w*64+64)
            sh.b.sidx[w][row - w*ROWS_PER_WAVE] = (unsigned char)(he - row*RR);
        }
    }

    // (6) row parameters from wave-local tables (lgkmcnt by compiler).
    const int true_r = (int)sh.b.sidx[w][lane];
    const int lhs    = sh.b.swl[w][true_r];
    const unsigned int mw0 = sh.b.swb[w][lhs*4 + 0];
    const unsigned int mw1 = sh.b.swb[w][lhs*4 + 1];
    const unsigned int mw2 = sh.b.swb[w][lhs*4 + 2];

    // (7) wait for OUR stages (wave's own vmcnt) — the only drain, per-wave,
    // naturally staggered across the CU's 8 waves. Fence per rule #18.
    asm volatile("s_waitcnt vmcnt(0)" ::: "memory");
    __builtin_amdgcn_sched_barrier(0);

    // --- per-row compute from LDS (verbatim R5 math) ---
    const float4* xr = &sh.b.sx[(w*ROWS_PER_WAVE + lane)*F4ROW];

    // Pass A: masked row max.
    float mx = -1e30f;
    #pragma unroll
    for (int k = 0; k < F4ROW; ++k) {
        const float4 v = xr[k];
        #pragma unroll
        for (int c = 0; c < 4; ++c) {
            const int r = k*4 + c;
            const unsigned int mw = (r < 32) ? mw0 : ((r < 64) ? mw1 : mw2);
            const bool un = (mw >> (r & 31)) & 1u;
            const float xm = un ? (&v.x)[c] : -1e30f;
            mx = fmaxf(mx, xm);
        }
    }

    // Pass B: e_r = exp(x_r - mx) (masked -> 0), sum.
    float s = 0.f;
    #pragma unroll
    for (int k = 0; k < F4ROW; ++k) {
        const float4 v = xr[k];
        #pragma unroll
        for (int c = 0; c < 4; ++c) {
            const int r = k*4 + c;
            const unsigned int mw = (r < 32) ? mw0 : ((r < 64) ? mw1 : mw2);
            const bool un = (mw >> (r & 31)) & 1u;
            const float xm = un ? (&v.x)[c] : -1e30f;
            s += __expf(xm - mx);
        }
    }

    // Pass C: clamped log(1-p) over ALL r (log2-domain), plus p at target.
    const float inv = 1.f / s;
    float sum_l2 = 0.f;
    float p_true = 0.f;
    #pragma unroll
    for (int k = 0; k < F4ROW; ++k) {
        const float4 v = xr[k];
        #pragma unroll
        for (int c = 0; c < 4; ++c) {
            const int r = k*4 + c;
            const unsigned int mw = (r < 32) ? mw0 : ((r < 64) ? mw1 : mw2);
            const bool un = (mw >> (r & 31)) & 1u;
            const float xm = un ? (&v.x)[c] : -1e30f;
            const float ev = __expf(xm - mx);
            const float p  = ev * inv;
            const float l2 = __log2f(1.f - p);
            sum_l2 += fmaxf(l2, NLN2F);
            if (r == true_r) p_true = p;
        }
    }
    float row_sum = LN2F * sum_l2;
    // Swap the true_r element's non-target term for the target term.
    const float l1c_t = fmaxf(LN2F * __log2f(1.f - p_true), -100.f);
    const float lp_t  = fmaxf(__logf(p_true), -100.f);   // p_true==0 (masked) -> -100
    row_sum += lp_t - l1c_t;

    // Block reduce (identical grouping: wave butterfly, (s0+s1)+(s2+s3)).
    #pragma unroll
    for (int off = 32; off; off >>= 1) row_sum += __shfl_xor(row_sum, off, 64);
    if (lane == 0) sh.b.sm_red[w] = row_sum;
    __syncthreads();   // only block-wide barrier; nothing left outstanding
    if (tid == 0)
        partials[blockIdx.x] = (double)((sh.b.sm_red[0] + sh.b.sm_red[1]) + (sh.b.sm_red[2] + sh.b.sm_red[3]));
}

// Sum NBCE bce partials + NMOM mom partials with the right scales. (Unchanged.)
__global__ __launch_bounds__(256) void final_kernel(
    const double* __restrict__ partials, float* __restrict__ out)
{
    __shared__ double sred[4];
    const int tid = threadIdx.x;
    double s = 0.0;
    for (int k = NMOM + tid; k < NBLK; k += 256) s += partials[k];
    double m = (tid < NMOM) ? partials[tid] : 0.0;
    double val = s * (-(double)SS / TOTAL_ELEMS) + m;
    #pragma unroll
    for (int off = 32; off; off >>= 1) val += __shfl_xor(val, off, 64);
    if ((tid & 63) == 0) sred[tid >> 6] = val;
    __syncthreads();
    if (tid == 0) out[0] = (float)((sred[0] + sred[1]) + (sred[2] + sred[3]));
}

extern "C" void kernel_launch(void* const* d_in, const int* in_sizes, int n_in,
                              void* d_out, int out_size, void* d_ws, size_t ws_size,
                              hipStream_t stream) {
    const float* model  = (const float*)d_in[0];   // [B,S,R]
    const float* mu     = (const float*)d_in[1];   // [B,Z]
    // d_in[2] = log_var — unused by the reference output
    const float* target = (const float*)d_in[3];   // [B,S,R] one-hot
    const float* masks  = (const float*)d_in[4];   // [NLHS,R]
    const int*   ind    = (const int*)  d_in[5];   // [R]
    float* out  = (float*)d_out;
    double* acc = (double*)d_ws;   // [0..NMOM) mom partials, [NMOM..NBLK) bce partials

    fused_kernel<<<NBLK, ROWS_PER_BLOCK, 0, stream>>>(model, target, masks, ind, mu, acc);
    final_kernel<<<1, 256, 0, stream>>>(acc, out);
}